// Round 5
// baseline (272.688 us; speedup 1.0000x reference)
//
#include <hip/hip_runtime.h>
#include <stdint.h>

// TSB RNN, wave-per-row affine scan. 32-VGPR / full-grid-resident design.
//
// Per-step linear part is anti-diagonal => over step-PAIRS the map is
// diagonal: c1 -> P*c1 + U, c2 -> Q*c2 + V (independent 1-D affine scans).
// Wave (64 lanes) owns one row; T=4096 in 8 tiles of 512 (8 steps/lane),
// carrying (C1,C2) across tiles.
//
// MEASURED MODEL (r0-r4): time is invariant at ~85 us across three
// structurally different kernels at 4 waves/SIMD (VGPR-roundtrip r0,
// streamed r2, DMA+dbuf+prefetch r4) -- per-wave MLP tricks do nothing.
// Per-resident-wave HBM throughput is constant ~0.6 GB/s in EVERY round
// (r1: 24 w/CU -> 3.85 TB/s; r0/2/4: 10 w/CU -> 2.4 TB/s). Time = traffic
// / (0.6 GB/s x resident waves). Traffic is fixed at ~201 MB, so the only
// lever is RESIDENT WAVES WITHOUT SPILL TRAFFIC (r1/r3 spilled).
//
// This version is a true <=32-VGPR kernel:
//   - TILE=512 (CHUNK=8): register chunk is xc[8], not xc[16].
//   - shared row-0 X values are JIT-loaded from global in BOTH phase 1 and
//     phase 3 (same 2 KB, L1-hot; second read is free) -- no Xc[] array.
//   - own-row staging via global_load_lds DMA (no VGPR roundtrip), LDS
//     double-buffered 2x2KB/wave = 16 KB/block -> 8 blocks/CU fit LDS.
//   - VGPR 32 -> 8 waves/SIMD -> all 2048 blocks co-resident, ONE round.
//   - 16B-block XOR swizzle (physical slot = s ^ ((s>>3)&7), involution;
//     DMA dest linear, SOURCE lane-permuted lam = lane ^ ((lane>>3)&7)):
//     chunk reads / phase-3 writes / store-gather are bank-balanced b128.
//   - counted vmcnt per tile (never 0): at the buf(t) wait, the only ops
//     allowed outstanding are stores(t-1) [<=2] and DMA(t+1) [<=2]; both
//     are younger than buf(t)'s DMA (in-order retire) => vmcnt(4)
//     (vmcnt(2) at t=0 / t=NTILE-1). sched_barrier(0) pins ds_reads after.
// Known cost: 8x26 shuffles instead of 4x26 (scan count is per-tile fixed)
// -- ~2 us of extra work, paid for 2x occupancy.
// No __syncthreads anywhere: all LDS regions are wave-private.

constexpr int T_LEN = 4096;
constexpr int TILE  = 512;           // floats per tile
constexpr int NTILE = T_LEN / TILE;  // 8
constexpr int CHUNK = TILE / 64;     // 8 steps per lane per tile
constexpr int WPB   = 4;             // waves per 256-thread block

typedef const __attribute__((address_space(1))) uint32_t* gas_ptr;
typedef __attribute__((address_space(3))) uint32_t* las_ptr;

__device__ __forceinline__ void dma16(const float* g, float* l) {
    // 16 B per lane, global (per-lane addr) -> LDS (uniform base + lane*16)
    __builtin_amdgcn_global_load_lds((gas_ptr)g, (las_ptr)l, 16, 0, 0);
}

__global__ __launch_bounds__(256, 8) void tsb_scan_kernel(
    const float* __restrict__ x,       // (B, T)
    const float* __restrict__ alpha_p,
    const float* __restrict__ beta_p,
    float* __restrict__ out,           // (B, T)
    int B)
{
    __shared__ __align__(16) float lds[WPB * 2 * TILE];   // 16,384 B / block

    const int tid  = threadIdx.x;
    const int wave = tid >> 6;
    const int lane = tid & 63;
    const int row  = blockIdx.x * WPB + wave;   // grid exact (B % WPB == 0)

    float* const buf0 = &lds[wave * 2 * TILE];  // two 2 KB halves, private

    const float a   = alpha_p[0];      // wave-uniform -> SGPR
    const float b   = beta_p[0];
    const float oma = 1.0f - a;
    const float omb = 1.0f - b;

    const int lam = lane ^ ((lane >> 3) & 7);   // source-lane permutation
    const float* xrow = x + (size_t)row * T_LEN;

    // ---- prologue: DMA tile 0 into half 0 (2 ops x 1 KB) ----
    {
        const float* g = xrow + lam * 4;
        dma16(g,       buf0);
        dma16(g + 256, buf0 + 256);
    }

    float C1 = 0.f, C2 = 0.f;          // carry across tiles

#pragma unroll
    for (int t = 0; t < NTILE; ++t) {
        float* const buf = buf0 + (t & 1) * TILE;

        // ---- prefetch: DMA tile t+1 into the other half ----
        if (t < NTILE - 1) {
            float* const nbuf = buf0 + ((t + 1) & 1) * TILE;
            const float* g = xrow + (t + 1) * TILE + lam * 4;
            dma16(g,       nbuf);
            dma16(g + 256, nbuf + 256);
        }

        // buf(t) ready: ops younger than buf(t)'s DMA are stores(t-1) [<=2]
        // and DMA(t+1) [<=2]; in-order retire => counted wait, never 0.
        if (t == 0 || t == NTILE - 1)
            asm volatile("s_waitcnt vmcnt(2)" ::: "memory");
        else
            asm volatile("s_waitcnt vmcnt(4)" ::: "memory");
        __builtin_amdgcn_sched_barrier(0);

        // ---- own chunk: 2 bank-balanced b128 reads at swizzled slots ----
        float xc[CHUNK];
#pragma unroll
        for (int j = 0; j < 2; ++j) {
            int s  = 2 * lane + j;
            int sp = s ^ ((s >> 3) & 7);
            *(float4*)(xc + 4 * j) = *(const float4*)&buf[sp * 4];
        }

        // lane's shared-X chunk base (row 0 of this tile; 2 KB, L1-hot)
        const float* Xt = x + t * TILE + 8 * lane;

        // ---- phase 1: compose 4 step-pairs into (p,u | q,v);
        //      X JIT-loaded (compiler hoists the 4 independent loads) ----
        float p = 1.f, u = 0.f, q = 1.f, v = 0.f;
#pragma unroll
        for (int h = 0; h < CHUNK / 2; ++h) {
            float2 Xp = *(const float2*)(Xt + 2 * h);
            float x1 = xc[2 * h], x2 = xc[2 * h + 1];
            float nz1 = (x1 != 0.f) ? 1.f : 0.f;
            float nz2 = (x2 != 0.f) ? 1.f : 0.f;
            float k1  = (x1 != 0.f) ? oma : 1.f;
            float k2  = (x2 != 0.f) ? oma : 1.f;
            float P = omb * k1;
            float U = omb * a * nz1 * Xp.x + b * nz2;
            float Q = omb * k2;
            float V = b * k2 * nz1 + a * nz2 * Xp.y;
            u = P * u + U;  p = P * p;
            v = Q * v + V;  q = Q * q;
        }

        // ---- phase 2: inclusive shuffle scan over 64 lanes ----
#pragma unroll
        for (int off = 1; off < 64; off <<= 1) {
            float pi = __shfl_up(p, off, 64);
            float ui = __shfl_up(u, off, 64);
            float qi = __shfl_up(q, off, 64);
            float vi = __shfl_up(v, off, 64);
            if (lane >= off) {
                u = p * ui + u;  p = p * pi;
                v = q * vi + v;  q = q * qi;
            }
        }
        // lane entry state = exclusive prefix applied to tile carry
        float pp = __shfl_up(p, 1, 64), up = __shfl_up(u, 1, 64);
        float qp = __shfl_up(q, 1, 64), vp = __shfl_up(v, 1, 64);
        float c1 = (lane == 0) ? C1 : (pp * C1 + up);
        float c2 = (lane == 0) ? C2 : (qp * C2 + vp);
        // tile exit carry from lane 63's inclusive map (uses OLD C1,C2)
        float p63 = __shfl(p, 63, 64), u63 = __shfl(u, 63, 64);
        float q63 = __shfl(q, 63, 64), v63 = __shfl(v, 63, 64);
        float C1n = p63 * C1 + u63;
        float C2n = q63 * C2 + v63;
        C1 = C1n;  C2 = C2n;

        // ---- phase 3: exact replay (X re-read from L1-hot global);
        //      4 outputs at a time -> b128 write to same swizzled slot ----
#pragma unroll
        for (int j = 0; j < 2; ++j) {
            float o[4];
#pragma unroll
            for (int k = 0; k < 2; ++k) {
                int idx = 4 * j + 2 * k;
                float2 Xp = *(const float2*)(Xt + idx);
                float xA = xc[idx], xB = xc[idx + 1];
                bool  nzA = (xA != 0.f);
                float c2A = nzA ? (a * Xp.x + oma * c1) : c1;
                float c1A = (nzA ? b : 0.f) + omb * c2;
                bool  nzB = (xB != 0.f);
                float c2B = nzB ? (a * Xp.y + oma * c1A) : c1A;
                float c1B = (nzB ? b : 0.f) + omb * c2A;
                c1 = c1B;  c2 = c2B;
                o[2 * k]     = c1A * c2A;
                o[2 * k + 1] = c1B * c2B;
            }
            int s  = 2 * lane + j;
            int sp = s ^ ((s >> 3) & 7);
            *(float4*)&buf[sp * 4] = *(float4*)o;
        }

        // ---- store-gather (bank-balanced b128) + coalesced stores ----
        float4* or4 = (float4*)(out + (size_t)row * T_LEN + t * TILE);
#pragma unroll
        for (int i = 0; i < 2; ++i) {
            // logical slot 64*i + lane lives at physical 64*i + lam
            or4[i * 64 + lane] = *(const float4*)&buf[i * 256 + lam * 4];
        }
    }
}

extern "C" void kernel_launch(void* const* d_in, const int* in_sizes, int n_in,
                              void* d_out, int out_size, void* d_ws, size_t ws_size,
                              hipStream_t stream) {
    const float* x     = (const float*)d_in[0];
    const float* alpha = (const float*)d_in[1];
    const float* beta  = (const float*)d_in[2];
    float* out = (float*)d_out;

    const int B = in_sizes[0] / T_LEN;   // 8192
    const int blocks = (B + WPB - 1) / WPB;
    tsb_scan_kernel<<<blocks, 64 * WPB, 0, stream>>>(x, alpha, beta, out, B);
}

// Round 6
// 264.785 us; speedup vs baseline: 1.0298x; 1.0298x over previous
//
#include <hip/hip_runtime.h>
#include <stdint.h>

// TSB RNN, wave-per-row affine scan. 42-VGPR / 6-waves-per-SIMD design.
//
// Per-step linear part is anti-diagonal => over step-PAIRS the map is
// diagonal: c1 -> P*c1 + U, c2 -> Q*c2 + V (independent 1-D affine scans).
// Wave (64 lanes) owns one row; T=4096 in 8 tiles of 512 (8 steps/lane),
// carrying (C1,C2) across tiles.
//
// MEASURED MODEL (r0-r5):
//   - 4 waves/SIMD spill-free: 85 us, 2.4 TB/s useful (r0/r2/r4, three
//     different structures, identical time).
//   - 8 waves/SIMD ALWAYS spills (r1/r3/r5): the wave-scan live set is
//     ~38-40 VGPR (r5 scratch volume ~26 B/lane on a 32-reg cap), and
//     scratch traffic (55-220 MB) eats the occupancy gain.
//   - machine TOTAL throughput did scale with waves (2.4 -> 3.15-3.85),
//     so the untested clean cell is MORE WAVES + ZERO SPILL.
// This round: launch_bounds(256,6) => compiler cap floor(256/6)=42 VGPR.
// 38-40 fits 42 with margin => 6 waves/SIMD (24/CU, +50%) spill-free.
// Kernel body is byte-identical to r5 -- single-variable A/B on the bound.
//
// Structure (from r5): TILE=512 (xc[8]); shared row-0 X JIT-loaded from
// global in both phases (2 KB, cache-hot) -- no Xc[] array; own-row staged
// via global_load_lds DMA into double-buffered 2x2KB LDS halves; 16B-block
// XOR swizzle (slot s -> s ^ ((s>>3)&7), involution; DMA dest linear,
// source lane-permuted lam = lane ^ ((lane>>3)&7)) => bank-balanced b128
// reads/writes; counted vmcnt per tile (never 0): at the buf(t) wait the
// only outstanding-allowed ops are stores(t-1) [<=2] and DMA(t+1) [<=2].
// No __syncthreads anywhere: all LDS regions are wave-private.

constexpr int T_LEN = 4096;
constexpr int TILE  = 512;           // floats per tile
constexpr int NTILE = T_LEN / TILE;  // 8
constexpr int CHUNK = TILE / 64;     // 8 steps per lane per tile
constexpr int WPB   = 4;             // waves per 256-thread block

typedef const __attribute__((address_space(1))) uint32_t* gas_ptr;
typedef __attribute__((address_space(3))) uint32_t* las_ptr;

__device__ __forceinline__ void dma16(const float* g, float* l) {
    // 16 B per lane, global (per-lane addr) -> LDS (uniform base + lane*16)
    __builtin_amdgcn_global_load_lds((gas_ptr)g, (las_ptr)l, 16, 0, 0);
}

__global__ __launch_bounds__(256, 6) void tsb_scan_kernel(
    const float* __restrict__ x,       // (B, T)
    const float* __restrict__ alpha_p,
    const float* __restrict__ beta_p,
    float* __restrict__ out,           // (B, T)
    int B)
{
    __shared__ __align__(16) float lds[WPB * 2 * TILE];   // 16,384 B / block

    const int tid  = threadIdx.x;
    const int wave = tid >> 6;
    const int lane = tid & 63;
    const int row  = blockIdx.x * WPB + wave;   // grid exact (B % WPB == 0)

    float* const buf0 = &lds[wave * 2 * TILE];  // two 2 KB halves, private

    const float a   = alpha_p[0];      // wave-uniform -> SGPR
    const float b   = beta_p[0];
    const float oma = 1.0f - a;
    const float omb = 1.0f - b;

    const int lam = lane ^ ((lane >> 3) & 7);   // source-lane permutation
    const float* xrow = x + (size_t)row * T_LEN;

    // ---- prologue: DMA tile 0 into half 0 (2 ops x 1 KB) ----
    {
        const float* g = xrow + lam * 4;
        dma16(g,       buf0);
        dma16(g + 256, buf0 + 256);
    }

    float C1 = 0.f, C2 = 0.f;          // carry across tiles

#pragma unroll
    for (int t = 0; t < NTILE; ++t) {
        float* const buf = buf0 + (t & 1) * TILE;

        // ---- prefetch: DMA tile t+1 into the other half ----
        if (t < NTILE - 1) {
            float* const nbuf = buf0 + ((t + 1) & 1) * TILE;
            const float* g = xrow + (t + 1) * TILE + lam * 4;
            dma16(g,       nbuf);
            dma16(g + 256, nbuf + 256);
        }

        // buf(t) ready: ops younger than buf(t)'s DMA are stores(t-1) [<=2]
        // and DMA(t+1) [<=2]; in-order retire => counted wait, never 0.
        if (t == 0 || t == NTILE - 1)
            asm volatile("s_waitcnt vmcnt(2)" ::: "memory");
        else
            asm volatile("s_waitcnt vmcnt(4)" ::: "memory");
        __builtin_amdgcn_sched_barrier(0);

        // ---- own chunk: 2 bank-balanced b128 reads at swizzled slots ----
        float xc[CHUNK];
#pragma unroll
        for (int j = 0; j < 2; ++j) {
            int s  = 2 * lane + j;
            int sp = s ^ ((s >> 3) & 7);
            *(float4*)(xc + 4 * j) = *(const float4*)&buf[sp * 4];
        }

        // lane's shared-X chunk base (row 0 of this tile; 2 KB, cache-hot)
        const float* Xt = x + t * TILE + 8 * lane;

        // ---- phase 1: compose 4 step-pairs into (p,u | q,v);
        //      X JIT-loaded (compiler hoists the 4 independent loads) ----
        float p = 1.f, u = 0.f, q = 1.f, v = 0.f;
#pragma unroll
        for (int h = 0; h < CHUNK / 2; ++h) {
            float2 Xp = *(const float2*)(Xt + 2 * h);
            float x1 = xc[2 * h], x2 = xc[2 * h + 1];
            float nz1 = (x1 != 0.f) ? 1.f : 0.f;
            float nz2 = (x2 != 0.f) ? 1.f : 0.f;
            float k1  = (x1 != 0.f) ? oma : 1.f;
            float k2  = (x2 != 0.f) ? oma : 1.f;
            float P = omb * k1;
            float U = omb * a * nz1 * Xp.x + b * nz2;
            float Q = omb * k2;
            float V = b * k2 * nz1 + a * nz2 * Xp.y;
            u = P * u + U;  p = P * p;
            v = Q * v + V;  q = Q * q;
        }

        // ---- phase 2: inclusive shuffle scan over 64 lanes ----
#pragma unroll
        for (int off = 1; off < 64; off <<= 1) {
            float pi = __shfl_up(p, off, 64);
            float ui = __shfl_up(u, off, 64);
            float qi = __shfl_up(q, off, 64);
            float vi = __shfl_up(v, off, 64);
            if (lane >= off) {
                u = p * ui + u;  p = p * pi;
                v = q * vi + v;  q = q * qi;
            }
        }
        // lane entry state = exclusive prefix applied to tile carry
        float pp = __shfl_up(p, 1, 64), up = __shfl_up(u, 1, 64);
        float qp = __shfl_up(q, 1, 64), vp = __shfl_up(v, 1, 64);
        float c1 = (lane == 0) ? C1 : (pp * C1 + up);
        float c2 = (lane == 0) ? C2 : (qp * C2 + vp);
        // tile exit carry from lane 63's inclusive map (uses OLD C1,C2)
        float p63 = __shfl(p, 63, 64), u63 = __shfl(u, 63, 64);
        float q63 = __shfl(q, 63, 64), v63 = __shfl(v, 63, 64);
        float C1n = p63 * C1 + u63;
        float C2n = q63 * C2 + v63;
        C1 = C1n;  C2 = C2n;

        // ---- phase 3: exact replay (X re-read from cache-hot global);
        //      4 outputs at a time -> b128 write to same swizzled slot ----
#pragma unroll
        for (int j = 0; j < 2; ++j) {
            float o[4];
#pragma unroll
            for (int k = 0; k < 2; ++k) {
                int idx = 4 * j + 2 * k;
                float2 Xp = *(const float2*)(Xt + idx);
                float xA = xc[idx], xB = xc[idx + 1];
                bool  nzA = (xA != 0.f);
                float c2A = nzA ? (a * Xp.x + oma * c1) : c1;
                float c1A = (nzA ? b : 0.f) + omb * c2;
                bool  nzB = (xB != 0.f);
                float c2B = nzB ? (a * Xp.y + oma * c1A) : c1A;
                float c1B = (nzB ? b : 0.f) + omb * c2A;
                c1 = c1B;  c2 = c2B;
                o[2 * k]     = c1A * c2A;
                o[2 * k + 1] = c1B * c2B;
            }
            int s  = 2 * lane + j;
            int sp = s ^ ((s >> 3) & 7);
            *(float4*)&buf[sp * 4] = *(float4*)o;
        }

        // ---- store-gather (bank-balanced b128) + coalesced stores ----
        float4* or4 = (float4*)(out + (size_t)row * T_LEN + t * TILE);
#pragma unroll
        for (int i = 0; i < 2; ++i) {
            // logical slot 64*i + lane lives at physical 64*i + lam
            or4[i * 64 + lane] = *(const float4*)&buf[i * 256 + lam * 4];
        }
    }
}

extern "C" void kernel_launch(void* const* d_in, const int* in_sizes, int n_in,
                              void* d_out, int out_size, void* d_ws, size_t ws_size,
                              hipStream_t stream) {
    const float* x     = (const float*)d_in[0];
    const float* alpha = (const float*)d_in[1];
    const float* beta  = (const float*)d_in[2];
    float* out = (float*)d_out;

    const int B = in_sizes[0] / T_LEN;   // 8192
    const int blocks = (B + WPB - 1) / WPB;
    tsb_scan_kernel<<<blocks, 64 * WPB, 0, stream>>>(x, alpha, beta, out, B);
}

// Round 7
// 254.160 us; speedup vs baseline: 1.0729x; 1.0418x over previous
//
#include <hip/hip_runtime.h>

// TSB RNN, wave-per-row affine scan. r2 streaming body @ 6 waves/SIMD.
//
// Per-step linear part is anti-diagonal => over step-PAIRS the map is
// diagonal: c1 -> P*c1 + U, c2 -> Q*c2 + V (independent 1-D affine scans).
// Wave (64 lanes) owns one row; T=4096 in 4 tiles of 1024 (16 steps/lane),
// carrying (C1,C2) across tiles.
//
// MEASURED MODEL (r0-r6):
//   - 85 us floor at {TILE=1024, 4 waves/SIMD, spill-free} across THREE
//     different staging structures (reg-roundtrip / streamed / DMA+dbuf).
//   - every high-occupancy attempt so far either spilled (r1/r3/r5) or
//     doubled per-tile fixed work via TILE=512 (r6: 6 waves CLEAN but
//     105 us) -- the {TILE=1024, >4 waves, clean} cell is UNTESTED.
// This round tests exactly that cell, changing two things vs r2 (85 us,
// 52 VGPR): (a) Xc[16] register cache -> JIT float2 X loads from global
// (2 KB/tile, cache-hot, proven r5/r6), cutting live set to ~32-36;
// (b) __launch_bounds__(256,6) -> 42-VGPR cap, 6 waves/SIMD (+50%).
// Everything else is r2's body verbatim: streamed global->LDS scatter
// (no register tile), padded LDS (+2 dwords per 32 elems, PADREG=1088,
// float2 chunk access at cb = 16*lane + 2*(lane>>1)), float2 stream in
// phase 1/3, in-place output overwrite, coalesced float4 stores.
// LDS 17,408 B/block -> 9 blocks/CU; 6 needed for 6 waves/SIMD. No
// __syncthreads: all LDS regions wave-private, DS ops in-order.

constexpr int T_LEN  = 4096;
constexpr int TILE   = 1024;
constexpr int NTILE  = T_LEN / TILE;           // 4
constexpr int CHUNK  = TILE / 64;              // 16 steps per lane per tile
constexpr int WPB    = 4;                      // waves per 256-thread block
constexpr int PADREG = TILE + 2 * (TILE / 32); // 1088 dwords per region

__global__ __launch_bounds__(256, 6) void tsb_scan_kernel(
    const float* __restrict__ x,       // (B, T)
    const float* __restrict__ alpha_p,
    const float* __restrict__ beta_p,
    float* __restrict__ out,           // (B, T)
    int B)
{
    __shared__ float lds[WPB * PADREG];   // 17,408 B / block

    const int tid  = threadIdx.x;
    const int wave = tid >> 6;
    const int lane = tid & 63;
    int row = blockIdx.x * WPB + wave;
    if (row >= B) row = B - 1;            // grid exact; benign duplicate

    float* xl = &lds[wave * PADREG];      // own-row tile (reused for output)

    const float a   = alpha_p[0];         // wave-uniform -> SGPR
    const float b   = beta_p[0];
    const float oma = 1.0f - a;
    const float omb = 1.0f - b;

    // padded chunk base: elements [16*lane .. 16*lane+15] map to
    // contiguous padded addrs [cb .. cb+15] (pad lands every 32 elems).
    const int cb = 16 * lane + 2 * (lane >> 1);

    float C1 = 0.f, C2 = 0.f;             // carry across tiles

    for (int t = 0; t < NTILE; ++t) {
        const float4* xr4 = (const float4*)(x + (size_t)row * T_LEN + t * TILE);

        // ---- own row: coalesced global load, streamed scatter to LDS ----
#pragma unroll
        for (int i = 0; i < 4; ++i) {
            float4 vx = xr4[i * 64 + lane];
            int e0 = i * 256 + 4 * lane;        // element idx of quad start
            int bq = e0 + 2 * (e0 >> 5);        // padded addr (8B-aligned)
            *(float2*)&xl[bq]     = make_float2(vx.x, vx.y);
            *(float2*)&xl[bq + 2] = make_float2(vx.z, vx.w);
        }

        // lane's shared-X chunk base (row 0 of this tile; 4 KB, cache-hot;
        // JIT float2 loads in both phases instead of a Xc[16] reg cache)
        const float* Xt = x + t * TILE + 16 * lane;

        // ---- phase 1: compose 8 step-pairs into (p,u | q,v),
        //      streaming x pairs from LDS and X pairs from global ----
        float p = 1.f, u = 0.f, q = 1.f, v = 0.f;
#pragma unroll
        for (int h = 0; h < CHUNK / 2; ++h) {
            float2 xp = *(const float2*)&xl[cb + 2 * h];
            float2 Xp = *(const float2*)(Xt + 2 * h);
            float x1 = xp.x, x2 = xp.y;
            float nz1 = (x1 != 0.f) ? 1.f : 0.f;
            float nz2 = (x2 != 0.f) ? 1.f : 0.f;
            float k1  = (x1 != 0.f) ? oma : 1.f;
            float k2  = (x2 != 0.f) ? oma : 1.f;
            float P = omb * k1;
            float U = omb * a * nz1 * Xp.x + b * nz2;
            float Q = omb * k2;
            float V = b * k2 * nz1 + a * nz2 * Xp.y;
            u = P * u + U;  p = P * p;
            v = Q * v + V;  q = Q * q;
        }

        // ---- phase 2: inclusive shuffle scan over 64 lanes ----
#pragma unroll
        for (int off = 1; off < 64; off <<= 1) {
            float pi = __shfl_up(p, off, 64);
            float ui = __shfl_up(u, off, 64);
            float qi = __shfl_up(q, off, 64);
            float vi = __shfl_up(v, off, 64);
            if (lane >= off) {
                u = p * ui + u;  p = p * pi;
                v = q * vi + v;  q = q * qi;
            }
        }
        // lane entry state = exclusive prefix applied to tile carry
        float pp = __shfl_up(p, 1, 64), up = __shfl_up(u, 1, 64);
        float qp = __shfl_up(q, 1, 64), vp = __shfl_up(v, 1, 64);
        float c1 = (lane == 0) ? C1 : (pp * C1 + up);
        float c2 = (lane == 0) ? C2 : (qp * C2 + vp);
        // tile exit carry from lane 63's inclusive map (uses OLD C1,C2)
        float p63 = __shfl(p, 63, 64), u63 = __shfl(u, 63, 64);
        float q63 = __shfl(q, 63, 64), v63 = __shfl(v, 63, 64);
        float C1n = p63 * C1 + u63;
        float C2n = q63 * C2 + v63;
        C1 = C1n;  C2 = C2n;

        // ---- phase 3: exact replay, streaming x pairs back from LDS
        //      (and X pairs from cache-hot global), overwriting outputs
        //      in place (wave-private region, DS in-order) ----
#pragma unroll
        for (int h = 0; h < CHUNK / 2; ++h) {
            float2 xp = *(const float2*)&xl[cb + 2 * h];
            float2 Xp = *(const float2*)(Xt + 2 * h);
            // step 2h
            bool  nzA = (xp.x != 0.f);
            float c2A = nzA ? (a * Xp.x + oma * c1) : c1;
            float c1A = (nzA ? b : 0.f) + omb * c2;
            // step 2h+1
            bool  nzB = (xp.y != 0.f);
            float c2B = nzB ? (a * Xp.y + oma * c1A) : c1A;
            float c1B = (nzB ? b : 0.f) + omb * c2A;
            c1 = c1B;  c2 = c2B;
            *(float2*)&xl[cb + 2 * h] = make_float2(c1A * c2A, c1B * c2B);
        }

        // ---- coalesced global stores (full lines) ----
        float4* or4 = (float4*)(out + (size_t)row * T_LEN + t * TILE);
#pragma unroll
        for (int i = 0; i < 4; ++i) {
            int e0 = i * 256 + 4 * lane;
            int bq = e0 + 2 * (e0 >> 5);
            float2 w0 = *(const float2*)&xl[bq];
            float2 w1 = *(const float2*)&xl[bq + 2];
            or4[i * 64 + lane] = make_float4(w0.x, w0.y, w1.x, w1.y);
        }
    }
}

extern "C" void kernel_launch(void* const* d_in, const int* in_sizes, int n_in,
                              void* d_out, int out_size, void* d_ws, size_t ws_size,
                              hipStream_t stream) {
    const float* x     = (const float*)d_in[0];
    const float* alpha = (const float*)d_in[1];
    const float* beta  = (const float*)d_in[2];
    float* out = (float*)d_out;

    const int B = in_sizes[0] / T_LEN;   // 8192
    const int blocks = (B + WPB - 1) / WPB;
    tsb_scan_kernel<<<blocks, 64 * WPB, 0, stream>>>(x, alpha, beta, out, B);
}

// Round 8
// 243.949 us; speedup vs baseline: 1.1178x; 1.0419x over previous
//
#include <hip/hip_runtime.h>

// TSB RNN, wave-per-TWO-rows affine scan. ILP-not-TLP design.
//
// Per-step linear part is anti-diagonal => over step-PAIRS the map is
// diagonal: c1 -> P*c1 + U, c2 -> Q*c2 + V (independent 1-D affine scans).
// Each wave owns TWO rows (A,B); T=4096 in 8 tiles of 512 (8 steps/lane),
// carrying (C1,C2) per row across tiles.
//
// MEASURED MODEL (r0-r7, 8 configs):
//   - clean 4 waves/SIMD = 85 us across THREE staging structures.
//   - >4 waves/SIMD = 105-112 us ALWAYS (clean or spill, TILE 512 or
//     1024): co-residency stretches the per-wave latency chain (queuing)
//     without adding throughput. Occupancy lever is closed.
//   - r1 (extra in-flight memory ops per wave) hit 3.85 TB/s machine
//     throughput: per-wave MLP is the one lever that moved bandwidth.
//   - time ~= generations x per-wave wall. 8192 single-row waves at
//     4/SIMD = 2 generations x ~42.5 us.
// This round: 2 rows/wave => 4096 waves = 1024 blocks = 4 blocks/CU =
// ONE generation at the proven-optimal 4 waves/SIMD. The two rows'
// chains interleave in one instruction stream (independent shfl pairs
// hide LDS-pipe latency; 2x loads in flight). Wall grows sub-2x =>
// predicted 55-70 us.
//
// Structure per row = r2's streamed body at TILE=512: coalesced float4
// loads -> padded-LDS scatter (pad +2 dwords per 32 elems, PADT=544;
// lane chunk contiguous at cb = 8*lane + 2*(lane>>2)); x streamed from
// LDS in phases 1 and 3 (no xc[] cache); shared row-0 X JIT-loaded as
// float2 from global (2 KB/tile, cache-hot; no Xc[] cache). Outputs
// overwrite the chunk in place; coalesced float4 stores.
// Plain __launch_bounds__(256): VGPR may land anywhere <=64; with only
// 1024 blocks, residency is 4 blocks/CU regardless. No __syncthreads:
// LDS regions wave-private, DS ops in-order.

constexpr int T_LEN = 4096;
constexpr int TILE  = 512;
constexpr int NTILE = T_LEN / TILE;        // 8
constexpr int WPB   = 4;                   // waves per 256-thread block
constexpr int PADT  = TILE + 2 * (TILE / 32); // 544 dwords per row buffer

__global__ __launch_bounds__(256) void tsb_scan_kernel(
    const float* __restrict__ x,       // (B, T)
    const float* __restrict__ alpha_p,
    const float* __restrict__ beta_p,
    float* __restrict__ out,           // (B, T)
    int B)
{
    __shared__ float lds[WPB * 2 * PADT];   // 17,408 B / block

    const int tid  = threadIdx.x;
    const int wave = tid >> 6;
    const int lane = tid & 63;
    int rowA = blockIdx.x * (2 * WPB) + 2 * wave;
    if (rowA + 1 >= B) rowA = B - 2;        // grid exact; benign clamp
    const int rowB = rowA + 1;

    float* bufA = &lds[wave * 2 * PADT];
    float* bufB = bufA + PADT;

    const float a   = alpha_p[0];           // wave-uniform -> SGPR
    const float b   = beta_p[0];
    const float oma = 1.0f - a;
    const float omb = 1.0f - b;

    // padded chunk base: elements [8*lane .. 8*lane+7] are contiguous in
    // padded space (pad +2 every 32 elems; a chunk never crosses a pad).
    const int cb = 8 * lane + 2 * (lane >> 2);

    float C1A = 0.f, C2A = 0.f, C1B = 0.f, C2B = 0.f;

    const float* xrA = x + (size_t)rowA * T_LEN;
    const float* xrB = x + (size_t)rowB * T_LEN;

    for (int t = 0; t < NTILE; ++t) {
        const float4* a4 = (const float4*)(xrA + t * TILE);
        const float4* b4 = (const float4*)(xrB + t * TILE);

        // ---- coalesced loads: 2 float4 per row per lane (full lines),
        //      both rows issued back-to-back => 4 loads in flight ----
        float4 va0 = a4[lane], va1 = a4[64 + lane];
        float4 vb0 = b4[lane], vb1 = b4[64 + lane];

        // ---- scatter to padded LDS (float2 writes, 8B-aligned) ----
        {
            int e0 = 4 * lane;        int q0 = e0 + 2 * (e0 >> 5);
            int e1 = 256 + 4 * lane;  int q1 = e1 + 2 * (e1 >> 5);
            *(float2*)&bufA[q0]     = make_float2(va0.x, va0.y);
            *(float2*)&bufA[q0 + 2] = make_float2(va0.z, va0.w);
            *(float2*)&bufA[q1]     = make_float2(va1.x, va1.y);
            *(float2*)&bufA[q1 + 2] = make_float2(va1.z, va1.w);
            *(float2*)&bufB[q0]     = make_float2(vb0.x, vb0.y);
            *(float2*)&bufB[q0 + 2] = make_float2(vb0.z, vb0.w);
            *(float2*)&bufB[q1]     = make_float2(vb1.x, vb1.y);
            *(float2*)&bufB[q1 + 2] = make_float2(vb1.z, vb1.w);
        }

        // lane's shared-X chunk base (row 0 of this tile; 2 KB, cache-hot)
        const float* Xt = x + t * TILE + 8 * lane;

        // ---- phase 1: compose 4 step-pairs, BOTH rows interleaved ----
        float pA = 1.f, uA = 0.f, qA = 1.f, vA = 0.f;
        float pB = 1.f, uB = 0.f, qB = 1.f, vB = 0.f;
#pragma unroll
        for (int h = 0; h < 4; ++h) {
            float2 Xp = *(const float2*)(Xt + 2 * h);
            float2 xa = *(const float2*)&bufA[cb + 2 * h];
            float2 xb = *(const float2*)&bufB[cb + 2 * h];
            {
                float nz1 = (xa.x != 0.f) ? 1.f : 0.f;
                float nz2 = (xa.y != 0.f) ? 1.f : 0.f;
                float k1  = (xa.x != 0.f) ? oma : 1.f;
                float k2  = (xa.y != 0.f) ? oma : 1.f;
                float P = omb * k1;
                float U = omb * a * nz1 * Xp.x + b * nz2;
                float Q = omb * k2;
                float V = b * k2 * nz1 + a * nz2 * Xp.y;
                uA = P * uA + U;  pA = P * pA;
                vA = Q * vA + V;  qA = Q * qA;
            }
            {
                float nz1 = (xb.x != 0.f) ? 1.f : 0.f;
                float nz2 = (xb.y != 0.f) ? 1.f : 0.f;
                float k1  = (xb.x != 0.f) ? oma : 1.f;
                float k2  = (xb.y != 0.f) ? oma : 1.f;
                float P = omb * k1;
                float U = omb * a * nz1 * Xp.x + b * nz2;
                float Q = omb * k2;
                float V = b * k2 * nz1 + a * nz2 * Xp.y;
                uB = P * uB + U;  pB = P * pB;
                vB = Q * vB + V;  qB = Q * qB;
            }
        }

        // ---- phase 2: inclusive shuffle scan, 8 independent quantities
        //      per stage (2 rows x 4) => LDS-pipe latency overlapped ----
#pragma unroll
        for (int off = 1; off < 64; off <<= 1) {
            float piA = __shfl_up(pA, off, 64), uiA = __shfl_up(uA, off, 64);
            float qiA = __shfl_up(qA, off, 64), viA = __shfl_up(vA, off, 64);
            float piB = __shfl_up(pB, off, 64), uiB = __shfl_up(uB, off, 64);
            float qiB = __shfl_up(qB, off, 64), viB = __shfl_up(vB, off, 64);
            if (lane >= off) {
                uA = pA * uiA + uA;  pA = pA * piA;
                vA = qA * viA + vA;  qA = qA * qiA;
                uB = pB * uiB + uB;  pB = pB * piB;
                vB = qB * viB + vB;  qB = qB * qiB;
            }
        }
        // lane entry state = exclusive prefix applied to tile carry
        float ppA = __shfl_up(pA, 1, 64), upA = __shfl_up(uA, 1, 64);
        float qpA = __shfl_up(qA, 1, 64), vpA = __shfl_up(vA, 1, 64);
        float ppB = __shfl_up(pB, 1, 64), upB = __shfl_up(uB, 1, 64);
        float qpB = __shfl_up(qB, 1, 64), vpB = __shfl_up(vB, 1, 64);
        float c1A = (lane == 0) ? C1A : (ppA * C1A + upA);
        float c2A = (lane == 0) ? C2A : (qpA * C2A + vpA);
        float c1B = (lane == 0) ? C1B : (ppB * C1B + upB);
        float c2B = (lane == 0) ? C2B : (qpB * C2B + vpB);
        // tile exit carries from lane 63's inclusive maps (OLD carries)
        float p63A = __shfl(pA, 63, 64), u63A = __shfl(uA, 63, 64);
        float q63A = __shfl(qA, 63, 64), v63A = __shfl(vA, 63, 64);
        float p63B = __shfl(pB, 63, 64), u63B = __shfl(uB, 63, 64);
        float q63B = __shfl(qB, 63, 64), v63B = __shfl(vB, 63, 64);
        float nC1A = p63A * C1A + u63A, nC2A = q63A * C2A + v63A;
        float nC1B = p63B * C1B + u63B, nC2B = q63B * C2B + v63B;
        C1A = nC1A;  C2A = nC2A;  C1B = nC1B;  C2B = nC2B;

        // ---- phase 3: exact replay, both rows; outputs overwrite the
        //      chunk slots in place (wave-private, DS in-order) ----
#pragma unroll
        for (int h = 0; h < 4; ++h) {
            float2 Xp = *(const float2*)(Xt + 2 * h);
            float2 xa = *(const float2*)&bufA[cb + 2 * h];
            float2 xb = *(const float2*)&bufB[cb + 2 * h];
            {
                bool  nz1 = (xa.x != 0.f);
                float c2n = nz1 ? (a * Xp.x + oma * c1A) : c1A;
                float c1n = (nz1 ? b : 0.f) + omb * c2A;
                bool  nz2 = (xa.y != 0.f);
                float c2m = nz2 ? (a * Xp.y + oma * c1n) : c1n;
                float c1m = (nz2 ? b : 0.f) + omb * c2n;
                c1A = c1m;  c2A = c2m;
                *(float2*)&bufA[cb + 2 * h] = make_float2(c1n * c2n, c1m * c2m);
            }
            {
                bool  nz1 = (xb.x != 0.f);
                float c2n = nz1 ? (a * Xp.x + oma * c1B) : c1B;
                float c1n = (nz1 ? b : 0.f) + omb * c2B;
                bool  nz2 = (xb.y != 0.f);
                float c2m = nz2 ? (a * Xp.y + oma * c1n) : c1n;
                float c1m = (nz2 ? b : 0.f) + omb * c2n;
                c1B = c1m;  c2B = c2m;
                *(float2*)&bufB[cb + 2 * h] = make_float2(c1n * c2n, c1m * c2m);
            }
        }

        // ---- coalesced global stores (full lines, both rows) ----
        float4* oA = (float4*)(out + (size_t)rowA * T_LEN + t * TILE);
        float4* oB = (float4*)(out + (size_t)rowB * T_LEN + t * TILE);
#pragma unroll
        for (int i = 0; i < 2; ++i) {
            int e0 = i * 256 + 4 * lane;
            int qq = e0 + 2 * (e0 >> 5);
            float2 wa0 = *(const float2*)&bufA[qq];
            float2 wa1 = *(const float2*)&bufA[qq + 2];
            float2 wb0 = *(const float2*)&bufB[qq];
            float2 wb1 = *(const float2*)&bufB[qq + 2];
            oA[i * 64 + lane] = make_float4(wa0.x, wa0.y, wa1.x, wa1.y);
            oB[i * 64 + lane] = make_float4(wb0.x, wb0.y, wb1.x, wb1.y);
        }
    }
}

extern "C" void kernel_launch(void* const* d_in, const int* in_sizes, int n_in,
                              void* d_out, int out_size, void* d_ws, size_t ws_size,
                              hipStream_t stream) {
    const float* x     = (const float*)d_in[0];
    const float* alpha = (const float*)d_in[1];
    const float* beta  = (const float*)d_in[2];
    float* out = (float*)d_out;

    const int B = in_sizes[0] / T_LEN;              // 8192
    const int rows_per_block = 2 * WPB;             // 8
    const int blocks = (B + rows_per_block - 1) / rows_per_block;  // 1024
    tsb_scan_kernel<<<blocks, 64 * WPB, 0, stream>>>(x, alpha, beta, out, B);
}